// Round 6
// baseline (79.391 us; speedup 1.0000x reference)
//
#include <hip/hip_runtime.h>
#include <math.h>

#define GEO_N 256

__device__ __forceinline__ float wredf(float v) {
#pragma unroll
  for (int off = 32; off; off >>= 1) v += __shfl_xor(v, off, 64);
  return v;
}

// Swizzle for a 3KB LDS region: injects byte-bits [9:7] into bank bits [6:4].
// Write pattern (j*1024 + lane*16, dense) stays dense; read pattern
// (lane*48 + k*16, 8-way conflicted) becomes conflict-free: lanes {l+8m}
// get distinct XOR offsets ((c+3m)&7)<<4  (3 coprime to 8).
__device__ __forceinline__ int swz(int a) { return a ^ (((a >> 7) & 7) << 4); }

// Halving butterfly: 16 per-lane values -> every lane holds ONE fully-reduced
// moment, index m(lane) = bitrev4(lane&15). 17 shfl + 17 add (vs 96+96).
__device__ __forceinline__ float hred16(const float r[16], int lane) {
  float v8[8], v4[4], v2[2], v1;
  const int b1 = lane & 1, b2 = (lane >> 1) & 1, b3 = (lane >> 2) & 1, b4 = (lane >> 3) & 1;
#pragma unroll
  for (int k = 0; k < 8; ++k) {
    float send = b1 ? r[k] : r[k + 8];
    float recv = __shfl_xor(send, 1, 64);
    v8[k] = (b1 ? r[k + 8] : r[k]) + recv;
  }
#pragma unroll
  for (int k = 0; k < 4; ++k) {
    float send = b2 ? v8[k] : v8[k + 4];
    float recv = __shfl_xor(send, 2, 64);
    v4[k] = (b2 ? v8[k + 4] : v8[k]) + recv;
  }
#pragma unroll
  for (int k = 0; k < 2; ++k) {
    float send = b3 ? v4[k] : v4[k + 2];
    float recv = __shfl_xor(send, 4, 64);
    v2[k] = (b3 ? v4[k + 2] : v4[k]) + recv;
  }
  {
    float send = b4 ? v2[0] : v2[1];
    float recv = __shfl_xor(send, 8, 64);
    v1 = (b4 ? v2[1] : v2[0]) + recv;
  }
  v1 += __shfl_xor(v1, 16, 64);
  v1 += __shfl_xor(v1, 32, 64);
  return v1;  // moment index: b4 + 2*b3 + 4*b2 + 8*b1 = bitrev4(lane&15)
}

// One Jacobi rotation on symmetric G (both sides) + accumulate into V.
template <int P, int Q>
__device__ __forceinline__ void jrot(float G[3][3], float V[3][3]) {
  float apq = G[P][Q];
  if (fabsf(apq) < 1e-22f) return;
  float tau = (G[Q][Q] - G[P][P]) / (2.0f * apq);
  float tt = sqrtf(1.0f + tau * tau);
  float t = (tau >= 0.0f) ? (1.0f / (tau + tt)) : (1.0f / (tau - tt));
  float c = 1.0f / sqrtf(1.0f + t * t);
  float s = t * c;
#pragma unroll
  for (int k = 0; k < 3; ++k) {
    float gkp = G[k][P], gkq = G[k][Q];
    G[k][P] = c * gkp - s * gkq;
    G[k][Q] = s * gkp + c * gkq;
  }
#pragma unroll
  for (int k = 0; k < 3; ++k) {
    float gpk = G[P][k], gqk = G[Q][k];
    G[P][k] = c * gpk - s * gqk;
    G[Q][k] = s * gpk + c * gqk;
  }
#pragma unroll
  for (int k = 0; k < 3; ++k) {
    float vkp = V[k][P], vkq = V[k][Q];
    V[k][P] = c * vkp - s * vkq;
    V[k][Q] = s * vkp + c * vkq;
  }
}

// From 16 raw moment sums -> R(9), scale, T(3) packed into bc[0..12].
__device__ __forceinline__ void solve_rst(const float s0[16], float bc[13]) {
  const float invN = 1.0f / (float)GEO_N;
  const float smx = s0[0] * invN, smy = s0[1] * invN, smz = s0[2] * invN;
  const float dmx = s0[3] * invN, dmy = s0[4] * invN, dmz = s0[5] * invN;
  float A[3][3];
  A[0][0] = s0[6] * invN - dmx * smx;  A[0][1] = s0[7] * invN - dmx * smy;  A[0][2] = s0[8] * invN - dmx * smz;
  A[1][0] = s0[9] * invN - dmy * smx;  A[1][1] = s0[10] * invN - dmy * smy; A[1][2] = s0[11] * invN - dmy * smz;
  A[2][0] = s0[12] * invN - dmz * smx; A[2][1] = s0[13] * invN - dmz * smy; A[2][2] = s0[14] * invN - dmz * smz;
  const float var_sum = s0[15] * invN - (smx * smx + smy * smy + smz * smz);

  float G[3][3];
#pragma unroll
  for (int i = 0; i < 3; ++i)
#pragma unroll
    for (int j = 0; j < 3; ++j)
      G[i][j] = A[0][i] * A[0][j] + A[1][i] * A[1][j] + A[2][i] * A[2][j];
  float V[3][3] = {{1, 0, 0}, {0, 1, 0}, {0, 0, 1}};
#pragma unroll 1
  for (int sweep = 0; sweep < 8; ++sweep) {
    float off = G[0][1] * G[0][1] + G[0][2] * G[0][2] + G[1][2] * G[1][2];
    float dia = G[0][0] * G[0][0] + G[1][1] * G[1][1] + G[2][2] * G[2][2];
    if (off <= 1e-13f * dia + 1e-30f) break;
    jrot<0, 1>(G, V);
    jrot<0, 2>(G, V);
    jrot<1, 2>(G, V);
  }
  float l0 = G[0][0], l1 = G[1][1], l2 = G[2][2];
  if (l0 < l1) { float tl = l0; l0 = l1; l1 = tl;
#pragma unroll
    for (int k = 0; k < 3; ++k) { float tv = V[k][0]; V[k][0] = V[k][1]; V[k][1] = tv; } }
  if (l0 < l2) { float tl = l0; l0 = l2; l2 = tl;
#pragma unroll
    for (int k = 0; k < 3; ++k) { float tv = V[k][0]; V[k][0] = V[k][2]; V[k][2] = tv; } }
  if (l1 < l2) { float tl = l1; l1 = l2; l2 = tl;
#pragma unroll
    for (int k = 0; k < 3; ++k) { float tv = V[k][1]; V[k][1] = V[k][2]; V[k][2] = tv; } }
  const float sig0 = sqrtf(fmaxf(l0, 0.0f));
  const float sig1 = sqrtf(fmaxf(l1, 0.0f));
  const float sig2 = sqrtf(fmaxf(l2, 0.0f));

  float v0[3] = {V[0][0], V[1][0], V[2][0]};
  float v1[3] = {V[0][1], V[1][1], V[2][1]};
  float v2[3] = {V[0][2], V[1][2], V[2][2]};
  float u0[3], u1[3], u2r[3];
#pragma unroll
  for (int i = 0; i < 3; ++i) {
    u0[i]  = A[i][0] * v0[0] + A[i][1] * v0[1] + A[i][2] * v0[2];
    u1[i]  = A[i][0] * v1[0] + A[i][1] * v1[1] + A[i][2] * v1[2];
    u2r[i] = A[i][0] * v2[0] + A[i][1] * v2[1] + A[i][2] * v2[2];
  }
  float n0 = u0[0] * u0[0] + u0[1] * u0[1] + u0[2] * u0[2];
  if (n0 > 1e-28f) { float inv = 1.0f / sqrtf(n0); u0[0] *= inv; u0[1] *= inv; u0[2] *= inv; }
  else { u0[0] = 1.0f; u0[1] = 0.0f; u0[2] = 0.0f; }
  float d01 = u1[0] * u0[0] + u1[1] * u0[1] + u1[2] * u0[2];
  u1[0] -= d01 * u0[0]; u1[1] -= d01 * u0[1]; u1[2] -= d01 * u0[2];
  float n1 = u1[0] * u1[0] + u1[1] * u1[1] + u1[2] * u1[2];
  if (n1 > 1e-28f) { float inv = 1.0f / sqrtf(n1); u1[0] *= inv; u1[1] *= inv; u1[2] *= inv; }
  else {
    float ex[3] = {1, 0, 0}, ey[3] = {0, 1, 0};
    const float* e = (fabsf(u0[0]) < 0.9f) ? ex : ey;
    u1[0] = u0[1] * e[2] - u0[2] * e[1];
    u1[1] = u0[2] * e[0] - u0[0] * e[2];
    u1[2] = u0[0] * e[1] - u0[1] * e[0];
    float nn = u1[0] * u1[0] + u1[1] * u1[1] + u1[2] * u1[2];
    float inv = 1.0f / sqrtf(nn);
    u1[0] *= inv; u1[1] *= inv; u1[2] *= inv;
  }
  float u2[3] = {u0[1] * u1[2] - u0[2] * u1[1],
                 u0[2] * u1[0] - u0[0] * u1[2],
                 u0[0] * u1[1] - u0[1] * u1[0]};
  float d2 = u2[0] * u2r[0] + u2[1] * u2r[1] + u2[2] * u2r[2];
  if (d2 < 0.0f) { u2[0] = -u2[0]; u2[1] = -u2[1]; u2[2] = -u2[2]; }

  const float scale = (sig0 + sig1 + sig2) / fmaxf(var_sum, 1e-30f);
  float R[3][3];
#pragma unroll
  for (int i = 0; i < 3; ++i)
#pragma unroll
    for (int j = 0; j < 3; ++j)
      R[i][j] = u0[i] * v0[j] + u1[i] * v1[j] + u2[i] * v2[j];
  const float Tx = dmx - scale * (R[0][0] * smx + R[0][1] * smy + R[0][2] * smz);
  const float Ty = dmy - scale * (R[1][0] * smx + R[1][1] * smy + R[1][2] * smz);
  const float Tz = dmz - scale * (R[2][0] * smx + R[2][1] * smy + R[2][2] * smz);
#pragma unroll
  for (int i = 0; i < 3; ++i)
#pragma unroll
    for (int j = 0; j < 3; ++j) bc[3 * i + j] = R[i][j];
  bc[9] = scale; bc[10] = Tx; bc[11] = Ty; bc[12] = Tz;
}

// Stage one batch (src+dst, 6KB) into this wave's LDS region via coalesced
// global loads + swizzled writes, then read back 4 whole points per lane.
// Must be followed by __syncthreads() by the CALLER between write and read;
// here we inline both phases around one barrier.
__device__ __forceinline__ void stage_and_read(const float* __restrict__ kp, int bsrc, int bdst,
                                               char* lds, int base, int lane,
                                               float s[12], float d[12]) {
  const float4* s4 = (const float4*)kp + (size_t)bsrc * 192;
  const float4* d4 = (const float4*)kp + (size_t)bdst * 192;
  float4 g0 = s4[lane], g1 = s4[64 + lane], g2 = s4[128 + lane];
  float4 h0 = d4[lane], h1 = d4[64 + lane], h2 = d4[128 + lane];
  *(float4*)(lds + base + swz(lane * 16))         = g0;
  *(float4*)(lds + base + swz(1024 + lane * 16))  = g1;
  *(float4*)(lds + base + swz(2048 + lane * 16))  = g2;
  *(float4*)(lds + base + 3072 + swz(lane * 16))        = h0;
  *(float4*)(lds + base + 3072 + swz(1024 + lane * 16)) = h1;
  *(float4*)(lds + base + 3072 + swz(2048 + lane * 16)) = h2;
  __syncthreads();
  float4 p0 = *(const float4*)(lds + base + swz(lane * 48 + 0));
  float4 p1 = *(const float4*)(lds + base + swz(lane * 48 + 16));
  float4 p2 = *(const float4*)(lds + base + swz(lane * 48 + 32));
  float4 q0 = *(const float4*)(lds + base + 3072 + swz(lane * 48 + 0));
  float4 q1 = *(const float4*)(lds + base + 3072 + swz(lane * 48 + 16));
  float4 q2 = *(const float4*)(lds + base + 3072 + swz(lane * 48 + 32));
  s[0] = p0.x; s[1] = p0.y; s[2] = p0.z; s[3] = p0.w;
  s[4] = p1.x; s[5] = p1.y; s[6] = p1.z; s[7] = p1.w;
  s[8] = p2.x; s[9] = p2.y; s[10] = p2.z; s[11] = p2.w;
  d[0] = q0.x; d[1] = q0.y; d[2] = q0.z; d[3] = q0.w;
  d[4] = q1.x; d[5] = q1.y; d[6] = q1.z; d[7] = q1.w;
  d[8] = q2.x; d[9] = q2.y; d[10] = q2.z; d[11] = q2.w;
}

// ---------- Kernel A: moments, one wave per batch, coalesced loads ----------
__global__ __launch_bounds__(256) void geo_momentsA(const float* __restrict__ kp,
                                                    const int* __restrict__ perm,
                                                    float* __restrict__ moments, int B) {
  __shared__ float4 lbuf[1536];  // 4 waves * 6KB
  char* lds = (char*)lbuf;
  const int w = threadIdx.x >> 6, lane = threadIdx.x & 63;
  const int b = (blockIdx.x << 2) | w;
  const int bb = min(b, B - 1);  // clamp (no early return: __syncthreads inside)

  float s[12], d[12];
  stage_and_read(kp, bb, perm[bb], lds, w * 6144, lane, s, d);

  float r[16];
#pragma unroll
  for (int k = 0; k < 16; ++k) r[k] = 0.0f;
#pragma unroll
  for (int p = 0; p < 4; ++p) {
    const float sx = s[3 * p + 0], sy = s[3 * p + 1], sz = s[3 * p + 2];
    const float dx = d[3 * p + 0], dy = d[3 * p + 1], dz = d[3 * p + 2];
    r[0] += sx; r[1] += sy; r[2] += sz;
    r[3] += dx; r[4] += dy; r[5] += dz;
    r[6] += dx * sx; r[7] += dx * sy; r[8] += dx * sz;
    r[9] += dy * sx; r[10] += dy * sy; r[11] += dy * sz;
    r[12] += dz * sx; r[13] += dz * sy; r[14] += dz * sz;
    r[15] += sx * sx + sy * sy + sz * sz;
  }
  float v = hred16(r, lane);  // lane j holds moment bitrev4(j&15)
  if (b < B && lane < 16) {
    const int m = ((lane & 1) << 3) | ((lane & 2) << 1) | ((lane & 4) >> 1) | ((lane & 8) >> 3);
    moments[(size_t)b * 16 + m] = v;
  }
}

// ---------- Kernel B: one THREAD per batch computes R/scale/T ----------
__global__ __launch_bounds__(256) void geo_svd(const float* __restrict__ moments,
                                               float* __restrict__ params, int B) {
  const int b = blockIdx.x * 256 + threadIdx.x;
  if (b >= B) return;
  const float4* m4 = (const float4*)moments + (size_t)b * 4;
  const float4 m0 = m4[0], m1 = m4[1], m2 = m4[2], m3 = m4[3];
  const float s0[16] = {m0.x, m0.y, m0.z, m0.w, m1.x, m1.y, m1.z, m1.w,
                        m2.x, m2.y, m2.z, m2.w, m3.x, m3.y, m3.z, m3.w};
  float bc[13];
  solve_rst(s0, bc);
  float4* p4 = (float4*)params + (size_t)b * 4;
  p4[0] = make_float4(bc[0], bc[1], bc[2], bc[3]);
  p4[1] = make_float4(bc[4], bc[5], bc[6], bc[7]);
  p4[2] = make_float4(bc[8], bc[9], bc[10], bc[11]);
  p4[3] = make_float4(bc[12], 0.0f, 0.0f, 0.0f);
}

// ---------- Kernel C: error sum, one wave per batch, coalesced loads ----------
__global__ __launch_bounds__(256) void geo_errC(const float* __restrict__ kp,
                                                const int* __restrict__ perm,
                                                const float* __restrict__ params,
                                                float* __restrict__ partials, int B) {
  __shared__ float4 lbuf[1536];
  char* lds = (char*)lbuf;
  const int w = threadIdx.x >> 6, lane = threadIdx.x & 63;
  const int b = (blockIdx.x << 2) | w;
  const int bb = min(b, B - 1);

  float s[12], d[12];
  stage_and_read(kp, bb, perm[bb], lds, w * 6144, lane, s, d);

  const float4* P4 = (const float4*)params + (size_t)bb * 4;
  const float4 P0 = P4[0], P1 = P4[1], P2 = P4[2], P3 = P4[3];
  const float R00 = P0.x, R01 = P0.y, R02 = P0.z, R10 = P0.w;
  const float R11 = P1.x, R12 = P1.y, R20 = P1.z, R21 = P1.w;
  const float R22 = P2.x, sc = P2.y, Tx = P2.z, Ty = P2.w, Tz = P3.x;

  float acc = 0.0f;
#pragma unroll
  for (int q = 0; q < 4; ++q) {
    const float sx = s[3 * q + 0], sy = s[3 * q + 1], sz = s[3 * q + 2];
    const float dx = d[3 * q + 0], dy = d[3 * q + 1], dz = d[3 * q + 2];
    const float e0 = sc * (R00 * sx + R01 * sy + R02 * sz) + Tx - dx;
    const float e1 = sc * (R10 * sx + R11 * sy + R12 * sz) + Ty - dy;
    const float e2 = sc * (R20 * sx + R21 * sy + R22 * sz) + Tz - dz;
    acc += fabsf(e0) + fabsf(e1) + fabsf(e2);
  }
  acc = wredf(acc);
  if (b < B && lane == 0) partials[b] = acc;
}

// ---------- Final reduce ----------
__global__ __launch_bounds__(1024) void geo_fin(const float* __restrict__ partials,
                                                float* __restrict__ out, int n,
                                                double inv_total) {
  const int t = threadIdx.x;
  double acc = 0.0;
  for (int i = t; i < n; i += 1024) acc += (double)partials[i];
#pragma unroll
  for (int off = 32; off; off >>= 1) acc += __shfl_xor(acc, off, 64);
  __shared__ double sred[16];
  if ((t & 63) == 0) sred[t >> 6] = acc;
  __syncthreads();
  if (t == 0) {
    double tot = 0.0;
#pragma unroll
    for (int k = 0; k < 16; ++k) tot += sred[k];
    out[0] = (float)(tot * inv_total);
  }
}

extern "C" void kernel_launch(void* const* d_in, const int* in_sizes, int n_in,
                              void* d_out, int out_size, void* d_ws, size_t ws_size,
                              hipStream_t stream) {
  const float* kp = (const float*)d_in[0];
  const int* perm = (const int*)d_in[1];
  float* out = (float*)d_out;
  const int B = in_sizes[1];
  const double inv_total = 1.0 / ((double)B * (double)GEO_N * 3.0);

  float* moments = (float*)d_ws;                // B*16
  float* params = moments + (size_t)B * 16;     // B*16
  float* partials = params + (size_t)B * 16;    // B

  const int gridW = (B + 3) / 4;  // one wave per batch, 4 waves/block
  geo_momentsA<<<gridW, 256, 0, stream>>>(kp, perm, moments, B);
  geo_svd<<<(B + 255) / 256, 256, 0, stream>>>(moments, params, B);
  geo_errC<<<gridW, 256, 0, stream>>>(kp, perm, params, partials, B);
  geo_fin<<<1, 1024, 0, stream>>>(partials, out, B, inv_total);
}

// Round 7
// 57.774 us; speedup vs baseline: 1.3742x; 1.3742x over previous
//
#include <hip/hip_runtime.h>
#include <math.h>

#define GEO_N 256

__device__ __forceinline__ float wredf(float v) {
#pragma unroll
  for (int off = 32; off; off >>= 1) v += __shfl_xor(v, off, 64);
  return v;
}

// Halving butterfly: 16 per-lane values -> every lane holds ONE fully-reduced
// moment, index m(lane) = bitrev4(lane&15). 17 shfl + 17 add (vs 96+96).
// Validated in round 6 (absmax 0).
__device__ __forceinline__ float hred16(const float r[16], int lane) {
  float v8[8], v4[4], v2[2], v1;
  const int b1 = lane & 1, b2 = (lane >> 1) & 1, b3 = (lane >> 2) & 1, b4 = (lane >> 3) & 1;
#pragma unroll
  for (int k = 0; k < 8; ++k) {
    float send = b1 ? r[k] : r[k + 8];
    float recv = __shfl_xor(send, 1, 64);
    v8[k] = (b1 ? r[k + 8] : r[k]) + recv;
  }
#pragma unroll
  for (int k = 0; k < 4; ++k) {
    float send = b2 ? v8[k] : v8[k + 4];
    float recv = __shfl_xor(send, 2, 64);
    v4[k] = (b2 ? v8[k + 4] : v8[k]) + recv;
  }
#pragma unroll
  for (int k = 0; k < 2; ++k) {
    float send = b3 ? v4[k] : v4[k + 2];
    float recv = __shfl_xor(send, 4, 64);
    v2[k] = (b3 ? v4[k + 2] : v4[k]) + recv;
  }
  {
    float send = b4 ? v2[0] : v2[1];
    float recv = __shfl_xor(send, 8, 64);
    v1 = (b4 ? v2[1] : v2[0]) + recv;
  }
  v1 += __shfl_xor(v1, 16, 64);
  v1 += __shfl_xor(v1, 32, 64);
  return v1;
}

// One Jacobi rotation on symmetric G (both sides) + accumulate into V.
template <int P, int Q>
__device__ __forceinline__ void jrot(float G[3][3], float V[3][3]) {
  float apq = G[P][Q];
  if (fabsf(apq) < 1e-22f) return;
  float tau = (G[Q][Q] - G[P][P]) / (2.0f * apq);
  float tt = sqrtf(1.0f + tau * tau);
  float t = (tau >= 0.0f) ? (1.0f / (tau + tt)) : (1.0f / (tau - tt));
  float c = 1.0f / sqrtf(1.0f + t * t);
  float s = t * c;
#pragma unroll
  for (int k = 0; k < 3; ++k) {
    float gkp = G[k][P], gkq = G[k][Q];
    G[k][P] = c * gkp - s * gkq;
    G[k][Q] = s * gkp + c * gkq;
  }
#pragma unroll
  for (int k = 0; k < 3; ++k) {
    float gpk = G[P][k], gqk = G[Q][k];
    G[P][k] = c * gpk - s * gqk;
    G[Q][k] = s * gpk + c * gqk;
  }
#pragma unroll
  for (int k = 0; k < 3; ++k) {
    float vkp = V[k][P], vkq = V[k][Q];
    V[k][P] = c * vkp - s * vkq;
    V[k][Q] = s * vkp + c * vkq;
  }
}

// From 16 raw moment sums -> R(9), scale, T(3) packed into bc[0..12].
// Validated rounds 1-6.
__device__ __forceinline__ void solve_rst(const float s0[16], float bc[13]) {
  const float invN = 1.0f / (float)GEO_N;
  const float smx = s0[0] * invN, smy = s0[1] * invN, smz = s0[2] * invN;
  const float dmx = s0[3] * invN, dmy = s0[4] * invN, dmz = s0[5] * invN;
  float A[3][3];
  A[0][0] = s0[6] * invN - dmx * smx;  A[0][1] = s0[7] * invN - dmx * smy;  A[0][2] = s0[8] * invN - dmx * smz;
  A[1][0] = s0[9] * invN - dmy * smx;  A[1][1] = s0[10] * invN - dmy * smy; A[1][2] = s0[11] * invN - dmy * smz;
  A[2][0] = s0[12] * invN - dmz * smx; A[2][1] = s0[13] * invN - dmz * smy; A[2][2] = s0[14] * invN - dmz * smz;
  const float var_sum = s0[15] * invN - (smx * smx + smy * smy + smz * smz);

  float G[3][3];
#pragma unroll
  for (int i = 0; i < 3; ++i)
#pragma unroll
    for (int j = 0; j < 3; ++j)
      G[i][j] = A[0][i] * A[0][j] + A[1][i] * A[1][j] + A[2][i] * A[2][j];
  float V[3][3] = {{1, 0, 0}, {0, 1, 0}, {0, 0, 1}};
#pragma unroll 1
  for (int sweep = 0; sweep < 8; ++sweep) {
    float off = G[0][1] * G[0][1] + G[0][2] * G[0][2] + G[1][2] * G[1][2];
    float dia = G[0][0] * G[0][0] + G[1][1] * G[1][1] + G[2][2] * G[2][2];
    if (off <= 1e-13f * dia + 1e-30f) break;
    jrot<0, 1>(G, V);
    jrot<0, 2>(G, V);
    jrot<1, 2>(G, V);
  }
  float l0 = G[0][0], l1 = G[1][1], l2 = G[2][2];
  if (l0 < l1) { float tl = l0; l0 = l1; l1 = tl;
#pragma unroll
    for (int k = 0; k < 3; ++k) { float tv = V[k][0]; V[k][0] = V[k][1]; V[k][1] = tv; } }
  if (l0 < l2) { float tl = l0; l0 = l2; l2 = tl;
#pragma unroll
    for (int k = 0; k < 3; ++k) { float tv = V[k][0]; V[k][0] = V[k][2]; V[k][2] = tv; } }
  if (l1 < l2) { float tl = l1; l1 = l2; l2 = tl;
#pragma unroll
    for (int k = 0; k < 3; ++k) { float tv = V[k][1]; V[k][1] = V[k][2]; V[k][2] = tv; } }
  const float sig0 = sqrtf(fmaxf(l0, 0.0f));
  const float sig1 = sqrtf(fmaxf(l1, 0.0f));
  const float sig2 = sqrtf(fmaxf(l2, 0.0f));

  float v0[3] = {V[0][0], V[1][0], V[2][0]};
  float v1[3] = {V[0][1], V[1][1], V[2][1]};
  float v2[3] = {V[0][2], V[1][2], V[2][2]};
  float u0[3], u1[3], u2r[3];
#pragma unroll
  for (int i = 0; i < 3; ++i) {
    u0[i]  = A[i][0] * v0[0] + A[i][1] * v0[1] + A[i][2] * v0[2];
    u1[i]  = A[i][0] * v1[0] + A[i][1] * v1[1] + A[i][2] * v1[2];
    u2r[i] = A[i][0] * v2[0] + A[i][1] * v2[1] + A[i][2] * v2[2];
  }
  float n0 = u0[0] * u0[0] + u0[1] * u0[1] + u0[2] * u0[2];
  if (n0 > 1e-28f) { float inv = 1.0f / sqrtf(n0); u0[0] *= inv; u0[1] *= inv; u0[2] *= inv; }
  else { u0[0] = 1.0f; u0[1] = 0.0f; u0[2] = 0.0f; }
  float d01 = u1[0] * u0[0] + u1[1] * u0[1] + u1[2] * u0[2];
  u1[0] -= d01 * u0[0]; u1[1] -= d01 * u0[1]; u1[2] -= d01 * u0[2];
  float n1 = u1[0] * u1[0] + u1[1] * u1[1] + u1[2] * u1[2];
  if (n1 > 1e-28f) { float inv = 1.0f / sqrtf(n1); u1[0] *= inv; u1[1] *= inv; u1[2] *= inv; }
  else {
    float ex[3] = {1, 0, 0}, ey[3] = {0, 1, 0};
    const float* e = (fabsf(u0[0]) < 0.9f) ? ex : ey;
    u1[0] = u0[1] * e[2] - u0[2] * e[1];
    u1[1] = u0[2] * e[0] - u0[0] * e[2];
    u1[2] = u0[0] * e[1] - u0[1] * e[0];
    float nn = u1[0] * u1[0] + u1[1] * u1[1] + u1[2] * u1[2];
    float inv = 1.0f / sqrtf(nn);
    u1[0] *= inv; u1[1] *= inv; u1[2] *= inv;
  }
  float u2[3] = {u0[1] * u1[2] - u0[2] * u1[1],
                 u0[2] * u1[0] - u0[0] * u1[2],
                 u0[0] * u1[1] - u0[1] * u1[0]};
  float d2 = u2[0] * u2r[0] + u2[1] * u2r[1] + u2[2] * u2r[2];
  if (d2 < 0.0f) { u2[0] = -u2[0]; u2[1] = -u2[1]; u2[2] = -u2[2]; }

  const float scale = (sig0 + sig1 + sig2) / fmaxf(var_sum, 1e-30f);
  float R[3][3];
#pragma unroll
  for (int i = 0; i < 3; ++i)
#pragma unroll
    for (int j = 0; j < 3; ++j)
      R[i][j] = u0[i] * v0[j] + u1[i] * v1[j] + u2[i] * v2[j];
  const float Tx = dmx - scale * (R[0][0] * smx + R[0][1] * smy + R[0][2] * smz);
  const float Ty = dmy - scale * (R[1][0] * smx + R[1][1] * smy + R[1][2] * smz);
  const float Tz = dmz - scale * (R[2][0] * smx + R[2][1] * smy + R[2][2] * smz);
#pragma unroll
  for (int i = 0; i < 3; ++i)
#pragma unroll
    for (int j = 0; j < 3; ++j) bc[3 * i + j] = R[i][j];
  bc[9] = scale; bc[10] = Tx; bc[11] = Ty; bc[12] = Tz;
}

// ---------- Block-cooperative fused kernel ----------
// Block = 4 waves = 16 batches (4 per wave).
// Phase 1: per-batch moments via hred16, parked in LDS.
// Phase 2: 16 threads (wave 0, lanes 0-15) solve the 16 batches once.
// Phase 3: re-read points (L2/L3-hot), params broadcast from LDS.
__global__ __launch_bounds__(256) void geo_block16(const float* __restrict__ kp,
                                                   const int* __restrict__ perm,
                                                   float* __restrict__ partials, int B) {
  __shared__ float lm[16][17];  // parked moments, pad 17 -> conflict-free solve reads
  __shared__ float lp[16][16];  // params R(9), scale, T(3)
  __shared__ float lred[4];
  const int tid = threadIdx.x;
  const int w = tid >> 6, lane = tid & 63;
  const int b0 = blockIdx.x * 16 + w * 4;  // this wave's first batch
  const float4* base = (const float4*)kp;

  // perm values for this wave's 4 batches, loaded once
  int pm[4];
#pragma unroll
  for (int i = 0; i < 4; ++i) pm[i] = perm[min(b0 + i, B - 1)];

  // ---- Phase 1: moments, depth-1 prefetch ----
  {
    const int bb = min(b0, B - 1);
    const float4* s4 = base + (size_t)bb * 192 + lane * 3;
    const float4* d4 = base + (size_t)pm[0] * 192 + lane * 3;
    float4 A0 = s4[0], A1 = s4[1], A2 = s4[2];
    float4 C0 = d4[0], C1 = d4[1], C2 = d4[2];
#pragma unroll 1
    for (int i = 0; i < 4; ++i) {
      float4 N0, N1, N2, M0, M1, M2;
      if (i < 3) {
        const int bn = min(b0 + i + 1, B - 1);
        const float4* sn = base + (size_t)bn * 192 + lane * 3;
        const float4* dn = base + (size_t)pm[i + 1] * 192 + lane * 3;
        N0 = sn[0]; N1 = sn[1]; N2 = sn[2];
        M0 = dn[0]; M1 = dn[1]; M2 = dn[2];
      }
      const float s[12] = {A0.x, A0.y, A0.z, A0.w, A1.x, A1.y, A1.z, A1.w, A2.x, A2.y, A2.z, A2.w};
      const float d[12] = {C0.x, C0.y, C0.z, C0.w, C1.x, C1.y, C1.z, C1.w, C2.x, C2.y, C2.z, C2.w};
      float r[16];
#pragma unroll
      for (int k = 0; k < 16; ++k) r[k] = 0.0f;
#pragma unroll
      for (int p = 0; p < 4; ++p) {
        const float sx = s[3 * p + 0], sy = s[3 * p + 1], sz = s[3 * p + 2];
        const float dx = d[3 * p + 0], dy = d[3 * p + 1], dz = d[3 * p + 2];
        r[0] += sx; r[1] += sy; r[2] += sz;
        r[3] += dx; r[4] += dy; r[5] += dz;
        r[6] += dx * sx; r[7] += dx * sy; r[8] += dx * sz;
        r[9] += dy * sx; r[10] += dy * sy; r[11] += dy * sz;
        r[12] += dz * sx; r[13] += dz * sy; r[14] += dz * sz;
        r[15] += sx * sx + sy * sy + sz * sz;
      }
      const float v = hred16(r, lane);
      if (lane < 16) {
        const int m = ((lane & 1) << 3) | ((lane & 2) << 1) | ((lane & 4) >> 1) | ((lane & 8) >> 3);
        lm[w * 4 + i][m] = v;
      }
      A0 = N0; A1 = N1; A2 = N2; C0 = M0; C1 = M1; C2 = M2;
    }
  }

  // Issue phase-3 batch-0 loads BEFORE the solve barrier: they stay in flight
  // across phase 2 (read-only data, no hazard), hiding solve latency.
  const int bb0 = min(b0, B - 1);
  const float4* s4b = base + (size_t)bb0 * 192 + lane * 3;
  const float4* d4b = base + (size_t)pm[0] * 192 + lane * 3;
  float4 A0 = s4b[0], A1 = s4b[1], A2 = s4b[2];
  float4 C0 = d4b[0], C1 = d4b[1], C2 = d4b[2];

  __syncthreads();

  // ---- Phase 2: one solve per batch, on 16 threads of wave 0 ----
  if (tid < 16) {
    float s0[16];
#pragma unroll
    for (int k = 0; k < 16; ++k) s0[k] = lm[tid][k];
    float bc[13];
    solve_rst(s0, bc);
#pragma unroll
    for (int k = 0; k < 13; ++k) lp[tid][k] = bc[k];
  }
  __syncthreads();

  // ---- Phase 3: errors, params broadcast from LDS ----
  float acc = 0.0f;
#pragma unroll 1
  for (int i = 0; i < 4; ++i) {
    float4 N0, N1, N2, M0, M1, M2;
    if (i < 3) {
      const int bn = min(b0 + i + 1, B - 1);
      const float4* sn = base + (size_t)bn * 192 + lane * 3;
      const float4* dn = base + (size_t)pm[i + 1] * 192 + lane * 3;
      N0 = sn[0]; N1 = sn[1]; N2 = sn[2];
      M0 = dn[0]; M1 = dn[1]; M2 = dn[2];
    }
    const int rI = w * 4 + i;
    const float R00 = lp[rI][0], R01 = lp[rI][1], R02 = lp[rI][2];
    const float R10 = lp[rI][3], R11 = lp[rI][4], R12 = lp[rI][5];
    const float R20 = lp[rI][6], R21 = lp[rI][7], R22 = lp[rI][8];
    const float sc = lp[rI][9], Tx = lp[rI][10], Ty = lp[rI][11], Tz = lp[rI][12];
    const float s[12] = {A0.x, A0.y, A0.z, A0.w, A1.x, A1.y, A1.z, A1.w, A2.x, A2.y, A2.z, A2.w};
    const float d[12] = {C0.x, C0.y, C0.z, C0.w, C1.x, C1.y, C1.z, C1.w, C2.x, C2.y, C2.z, C2.w};
    float a = 0.0f;
#pragma unroll
    for (int q = 0; q < 4; ++q) {
      const float sx = s[3 * q + 0], sy = s[3 * q + 1], sz = s[3 * q + 2];
      const float dx = d[3 * q + 0], dy = d[3 * q + 1], dz = d[3 * q + 2];
      const float e0 = sc * (R00 * sx + R01 * sy + R02 * sz) + Tx - dx;
      const float e1 = sc * (R10 * sx + R11 * sy + R12 * sz) + Ty - dy;
      const float e2 = sc * (R20 * sx + R21 * sy + R22 * sz) + Tz - dz;
      a += fabsf(e0) + fabsf(e1) + fabsf(e2);
    }
    if (b0 + i < B) acc += a;  // mask out clamped (OOB) batches
    A0 = N0; A1 = N1; A2 = N2; C0 = M0; C1 = M1; C2 = M2;
  }
  acc = wredf(acc);
  if (lane == 0) lred[w] = acc;
  __syncthreads();
  if (tid == 0) partials[blockIdx.x] = (lred[0] + lred[1]) + (lred[2] + lred[3]);
}

// ---------- Final reduce ----------
__global__ __launch_bounds__(1024) void geo_fin(const float* __restrict__ partials,
                                                float* __restrict__ out, int n,
                                                double inv_total) {
  const int t = threadIdx.x;
  double acc = 0.0;
  for (int i = t; i < n; i += 1024) acc += (double)partials[i];
#pragma unroll
  for (int off = 32; off; off >>= 1) acc += __shfl_xor(acc, off, 64);
  __shared__ double sred[16];
  if ((t & 63) == 0) sred[t >> 6] = acc;
  __syncthreads();
  if (t == 0) {
    double tot = 0.0;
#pragma unroll
    for (int k = 0; k < 16; ++k) tot += sred[k];
    out[0] = (float)(tot * inv_total);
  }
}

extern "C" void kernel_launch(void* const* d_in, const int* in_sizes, int n_in,
                              void* d_out, int out_size, void* d_ws, size_t ws_size,
                              hipStream_t stream) {
  const float* kp = (const float*)d_in[0];
  const int* perm = (const int*)d_in[1];
  float* out = (float*)d_out;
  const int B = in_sizes[1];
  const double inv_total = 1.0 / ((double)B * (double)GEO_N * 3.0);

  float* partials = (float*)d_ws;
  const int grid = (B + 15) / 16;  // 16 batches per 256-thread block
  geo_block16<<<grid, 256, 0, stream>>>(kp, perm, partials, B);
  geo_fin<<<1, 1024, 0, stream>>>(partials, out, grid, inv_total);
}

// Round 8
// 53.151 us; speedup vs baseline: 1.4937x; 1.0870x over previous
//
#include <hip/hip_runtime.h>
#include <math.h>

#define GEO_N 256

__device__ __forceinline__ float wredf(float v) {
#pragma unroll
  for (int off = 32; off; off >>= 1) v += __shfl_xor(v, off, 64);
  return v;
}

// Halving butterfly: 16 per-lane values -> every lane holds ONE fully-reduced
// moment, index m(lane) = bitrev4(lane&15). 17 shfl + 17 add. Validated r6/r7.
__device__ __forceinline__ float hred16(const float r[16], int lane) {
  float v8[8], v4[4], v2[2], v1;
  const int b1 = lane & 1, b2 = (lane >> 1) & 1, b3 = (lane >> 2) & 1, b4 = (lane >> 3) & 1;
#pragma unroll
  for (int k = 0; k < 8; ++k) {
    float send = b1 ? r[k] : r[k + 8];
    float recv = __shfl_xor(send, 1, 64);
    v8[k] = (b1 ? r[k + 8] : r[k]) + recv;
  }
#pragma unroll
  for (int k = 0; k < 4; ++k) {
    float send = b2 ? v8[k] : v8[k + 4];
    float recv = __shfl_xor(send, 2, 64);
    v4[k] = (b2 ? v8[k + 4] : v8[k]) + recv;
  }
#pragma unroll
  for (int k = 0; k < 2; ++k) {
    float send = b3 ? v4[k] : v4[k + 2];
    float recv = __shfl_xor(send, 4, 64);
    v2[k] = (b3 ? v4[k + 2] : v4[k]) + recv;
  }
  {
    float send = b4 ? v2[0] : v2[1];
    float recv = __shfl_xor(send, 8, 64);
    v1 = (b4 ? v2[1] : v2[0]) + recv;
  }
  v1 += __shfl_xor(v1, 16, 64);
  v1 += __shfl_xor(v1, 32, 64);
  return v1;
}

// One Jacobi rotation on symmetric G (both sides) + accumulate into V.
template <int P, int Q>
__device__ __forceinline__ void jrot(float G[3][3], float V[3][3]) {
  float apq = G[P][Q];
  if (fabsf(apq) < 1e-22f) return;
  float tau = (G[Q][Q] - G[P][P]) / (2.0f * apq);
  float tt = sqrtf(1.0f + tau * tau);
  float t = (tau >= 0.0f) ? (1.0f / (tau + tt)) : (1.0f / (tau - tt));
  float c = 1.0f / sqrtf(1.0f + t * t);
  float s = t * c;
#pragma unroll
  for (int k = 0; k < 3; ++k) {
    float gkp = G[k][P], gkq = G[k][Q];
    G[k][P] = c * gkp - s * gkq;
    G[k][Q] = s * gkp + c * gkq;
  }
#pragma unroll
  for (int k = 0; k < 3; ++k) {
    float gpk = G[P][k], gqk = G[Q][k];
    G[P][k] = c * gpk - s * gqk;
    G[Q][k] = s * gpk + c * gqk;
  }
#pragma unroll
  for (int k = 0; k < 3; ++k) {
    float vkp = V[k][P], vkq = V[k][Q];
    V[k][P] = c * vkp - s * vkq;
    V[k][Q] = s * vkp + c * vkq;
  }
}

// From 16 raw moment sums -> R(9), scale, T(3) packed into bc[0..12].
// Validated rounds 1-7.
__device__ __forceinline__ void solve_rst(const float s0[16], float bc[13]) {
  const float invN = 1.0f / (float)GEO_N;
  const float smx = s0[0] * invN, smy = s0[1] * invN, smz = s0[2] * invN;
  const float dmx = s0[3] * invN, dmy = s0[4] * invN, dmz = s0[5] * invN;
  float A[3][3];
  A[0][0] = s0[6] * invN - dmx * smx;  A[0][1] = s0[7] * invN - dmx * smy;  A[0][2] = s0[8] * invN - dmx * smz;
  A[1][0] = s0[9] * invN - dmy * smx;  A[1][1] = s0[10] * invN - dmy * smy; A[1][2] = s0[11] * invN - dmy * smz;
  A[2][0] = s0[12] * invN - dmz * smx; A[2][1] = s0[13] * invN - dmz * smy; A[2][2] = s0[14] * invN - dmz * smz;
  const float var_sum = s0[15] * invN - (smx * smx + smy * smy + smz * smz);

  float G[3][3];
#pragma unroll
  for (int i = 0; i < 3; ++i)
#pragma unroll
    for (int j = 0; j < 3; ++j)
      G[i][j] = A[0][i] * A[0][j] + A[1][i] * A[1][j] + A[2][i] * A[2][j];
  float V[3][3] = {{1, 0, 0}, {0, 1, 0}, {0, 0, 1}};
#pragma unroll 1
  for (int sweep = 0; sweep < 8; ++sweep) {
    float off = G[0][1] * G[0][1] + G[0][2] * G[0][2] + G[1][2] * G[1][2];
    float dia = G[0][0] * G[0][0] + G[1][1] * G[1][1] + G[2][2] * G[2][2];
    if (off <= 1e-13f * dia + 1e-30f) break;
    jrot<0, 1>(G, V);
    jrot<0, 2>(G, V);
    jrot<1, 2>(G, V);
  }
  float l0 = G[0][0], l1 = G[1][1], l2 = G[2][2];
  if (l0 < l1) { float tl = l0; l0 = l1; l1 = tl;
#pragma unroll
    for (int k = 0; k < 3; ++k) { float tv = V[k][0]; V[k][0] = V[k][1]; V[k][1] = tv; } }
  if (l0 < l2) { float tl = l0; l0 = l2; l2 = tl;
#pragma unroll
    for (int k = 0; k < 3; ++k) { float tv = V[k][0]; V[k][0] = V[k][2]; V[k][2] = tv; } }
  if (l1 < l2) { float tl = l1; l1 = l2; l2 = tl;
#pragma unroll
    for (int k = 0; k < 3; ++k) { float tv = V[k][1]; V[k][1] = V[k][2]; V[k][2] = tv; } }
  const float sig0 = sqrtf(fmaxf(l0, 0.0f));
  const float sig1 = sqrtf(fmaxf(l1, 0.0f));
  const float sig2 = sqrtf(fmaxf(l2, 0.0f));

  float v0[3] = {V[0][0], V[1][0], V[2][0]};
  float v1[3] = {V[0][1], V[1][1], V[2][1]};
  float v2[3] = {V[0][2], V[1][2], V[2][2]};
  float u0[3], u1[3], u2r[3];
#pragma unroll
  for (int i = 0; i < 3; ++i) {
    u0[i]  = A[i][0] * v0[0] + A[i][1] * v0[1] + A[i][2] * v0[2];
    u1[i]  = A[i][0] * v1[0] + A[i][1] * v1[1] + A[i][2] * v1[2];
    u2r[i] = A[i][0] * v2[0] + A[i][1] * v2[1] + A[i][2] * v2[2];
  }
  float n0 = u0[0] * u0[0] + u0[1] * u0[1] + u0[2] * u0[2];
  if (n0 > 1e-28f) { float inv = 1.0f / sqrtf(n0); u0[0] *= inv; u0[1] *= inv; u0[2] *= inv; }
  else { u0[0] = 1.0f; u0[1] = 0.0f; u0[2] = 0.0f; }
  float d01 = u1[0] * u0[0] + u1[1] * u0[1] + u1[2] * u0[2];
  u1[0] -= d01 * u0[0]; u1[1] -= d01 * u0[1]; u1[2] -= d01 * u0[2];
  float n1 = u1[0] * u1[0] + u1[1] * u1[1] + u1[2] * u1[2];
  if (n1 > 1e-28f) { float inv = 1.0f / sqrtf(n1); u1[0] *= inv; u1[1] *= inv; u1[2] *= inv; }
  else {
    float ex[3] = {1, 0, 0}, ey[3] = {0, 1, 0};
    const float* e = (fabsf(u0[0]) < 0.9f) ? ex : ey;
    u1[0] = u0[1] * e[2] - u0[2] * e[1];
    u1[1] = u0[2] * e[0] - u0[0] * e[2];
    u1[2] = u0[0] * e[1] - u0[1] * e[0];
    float nn = u1[0] * u1[0] + u1[1] * u1[1] + u1[2] * u1[2];
    float inv = 1.0f / sqrtf(nn);
    u1[0] *= inv; u1[1] *= inv; u1[2] *= inv;
  }
  float u2[3] = {u0[1] * u1[2] - u0[2] * u1[1],
                 u0[2] * u1[0] - u0[0] * u1[2],
                 u0[0] * u1[1] - u0[1] * u1[0]};
  float d2 = u2[0] * u2r[0] + u2[1] * u2r[1] + u2[2] * u2r[2];
  if (d2 < 0.0f) { u2[0] = -u2[0]; u2[1] = -u2[1]; u2[2] = -u2[2]; }

  const float scale = (sig0 + sig1 + sig2) / fmaxf(var_sum, 1e-30f);
  float R[3][3];
#pragma unroll
  for (int i = 0; i < 3; ++i)
#pragma unroll
    for (int j = 0; j < 3; ++j)
      R[i][j] = u0[i] * v0[j] + u1[i] * v1[j] + u2[i] * v2[j];
  const float Tx = dmx - scale * (R[0][0] * smx + R[0][1] * smy + R[0][2] * smz);
  const float Ty = dmy - scale * (R[1][0] * smx + R[1][1] * smy + R[1][2] * smz);
  const float Tz = dmz - scale * (R[2][0] * smx + R[2][1] * smy + R[2][2] * smz);
#pragma unroll
  for (int i = 0; i < 3; ++i)
#pragma unroll
    for (int j = 0; j < 3; ++j) bc[3 * i + j] = R[i][j];
  bc[9] = scale; bc[10] = Tx; bc[11] = Ty; bc[12] = Tz;
}

// ---------- Single-pass, barrier-free: one WAVE = 4 batches, all in VGPRs.
// Load 24 float4 up front -> moments + hred16 per batch, parked by lane-group
// -> shfl-transpose so lane t holds batch (t&3)'s 16 moments -> ONE solve per
// wave (every lane solves a real batch; Jacobi exit = max over 4 matrices)
// -> params broadcast by shfl -> error from still-live registers. No LDS, no
// barriers, no second HBM pass.
__global__ __launch_bounds__(256) void geo_wave4(const float* __restrict__ kp,
                                                 const int* __restrict__ perm,
                                                 float* __restrict__ partials,
                                                 int B, int NW) {
  const int wid = (blockIdx.x << 2) | (threadIdx.x >> 6);
  if (wid >= NW) return;  // no barriers in this kernel -> early return safe
  const int lane = threadIdx.x & 63;
  const int b0 = wid * 4;
  const float4* base = (const float4*)kp;

  int pm[4];
#pragma unroll
  for (int i = 0; i < 4; ++i) pm[i] = perm[min(b0 + i, B - 1)];

  // ---- Load all 4 batches (src + permuted dst): 24 loads in flight ----
  float4 S[4][3], D[4][3];
#pragma unroll
  for (int i = 0; i < 4; ++i) {
    const int bb = min(b0 + i, B - 1);
    const float4* s4 = base + (size_t)bb * 192 + lane * 3;
    const float4* d4 = base + (size_t)pm[i] * 192 + lane * 3;
    S[i][0] = s4[0]; S[i][1] = s4[1]; S[i][2] = s4[2];
    D[i][0] = d4[0]; D[i][1] = d4[1]; D[i][2] = d4[2];
  }

  // ---- Moments per batch; park batch i's reduced moments in lane-group i ----
  float parked = 0.0f;
#pragma unroll
  for (int i = 0; i < 4; ++i) {
    const float s[12] = {S[i][0].x, S[i][0].y, S[i][0].z, S[i][0].w,
                         S[i][1].x, S[i][1].y, S[i][1].z, S[i][1].w,
                         S[i][2].x, S[i][2].y, S[i][2].z, S[i][2].w};
    const float d[12] = {D[i][0].x, D[i][0].y, D[i][0].z, D[i][0].w,
                         D[i][1].x, D[i][1].y, D[i][1].z, D[i][1].w,
                         D[i][2].x, D[i][2].y, D[i][2].z, D[i][2].w};
    float r[16];
#pragma unroll
    for (int k = 0; k < 16; ++k) r[k] = 0.0f;
#pragma unroll
    for (int p = 0; p < 4; ++p) {
      const float sx = s[3 * p + 0], sy = s[3 * p + 1], sz = s[3 * p + 2];
      const float dx = d[3 * p + 0], dy = d[3 * p + 1], dz = d[3 * p + 2];
      r[0] += sx; r[1] += sy; r[2] += sz;
      r[3] += dx; r[4] += dy; r[5] += dz;
      r[6] += dx * sx; r[7] += dx * sy; r[8] += dx * sz;
      r[9] += dy * sx; r[10] += dy * sy; r[11] += dy * sz;
      r[12] += dz * sx; r[13] += dz * sy; r[14] += dz * sz;
      r[15] += sx * sx + sy * sy + sz * sz;
    }
    const float v = hred16(r, lane);  // lane j: moment bitrev4(j&15), all j
    if ((lane >> 4) == i) parked = v;
  }

  // ---- shfl-transpose: lane t gathers batch (t&3)'s 16 moments in order ----
  // parked[lane j] = moment bitrev4(j&15) of batch (j>>4). Moment k of batch
  // t is at lane (t<<4)|bitrev4(k). (lane<<4) wraps mod 64 -> batch lane&3.
  constexpr int br[16] = {0, 8, 4, 12, 2, 10, 6, 14, 1, 9, 5, 13, 3, 11, 7, 15};
  float s0[16];
#pragma unroll
  for (int k = 0; k < 16; ++k)
    s0[k] = __shfl(parked, ((lane & 3) << 4) | br[k], 64);

  // ---- One solve per wave (lane t solves batch b0 + (t&3)) ----
  float bc[13];
  solve_rst(s0, bc);

  // ---- Errors from live registers; params broadcast from lane i ----
  float acc = 0.0f;
#pragma unroll
  for (int i = 0; i < 4; ++i) {
    const float R00 = __shfl(bc[0], i, 64), R01 = __shfl(bc[1], i, 64), R02 = __shfl(bc[2], i, 64);
    const float R10 = __shfl(bc[3], i, 64), R11 = __shfl(bc[4], i, 64), R12 = __shfl(bc[5], i, 64);
    const float R20 = __shfl(bc[6], i, 64), R21 = __shfl(bc[7], i, 64), R22 = __shfl(bc[8], i, 64);
    const float sc  = __shfl(bc[9], i, 64);
    const float Tx  = __shfl(bc[10], i, 64), Ty = __shfl(bc[11], i, 64), Tz = __shfl(bc[12], i, 64);
    const float s[12] = {S[i][0].x, S[i][0].y, S[i][0].z, S[i][0].w,
                         S[i][1].x, S[i][1].y, S[i][1].z, S[i][1].w,
                         S[i][2].x, S[i][2].y, S[i][2].z, S[i][2].w};
    const float d[12] = {D[i][0].x, D[i][0].y, D[i][0].z, D[i][0].w,
                         D[i][1].x, D[i][1].y, D[i][1].z, D[i][1].w,
                         D[i][2].x, D[i][2].y, D[i][2].z, D[i][2].w};
    float a = 0.0f;
#pragma unroll
    for (int q = 0; q < 4; ++q) {
      const float sx = s[3 * q + 0], sy = s[3 * q + 1], sz = s[3 * q + 2];
      const float dx = d[3 * q + 0], dy = d[3 * q + 1], dz = d[3 * q + 2];
      const float e0 = sc * (R00 * sx + R01 * sy + R02 * sz) + Tx - dx;
      const float e1 = sc * (R10 * sx + R11 * sy + R12 * sz) + Ty - dy;
      const float e2 = sc * (R20 * sx + R21 * sy + R22 * sz) + Tz - dz;
      a += fabsf(e0) + fabsf(e1) + fabsf(e2);
    }
    if (b0 + i < B) acc += a;  // mask clamped tail batches
  }
  acc = wredf(acc);
  if (lane == 0) partials[wid] = acc;
}

// ---------- Final reduce ----------
__global__ __launch_bounds__(1024) void geo_fin(const float* __restrict__ partials,
                                                float* __restrict__ out, int n,
                                                double inv_total) {
  const int t = threadIdx.x;
  double acc = 0.0;
  for (int i = t; i < n; i += 1024) acc += (double)partials[i];
#pragma unroll
  for (int off = 32; off; off >>= 1) acc += __shfl_xor(acc, off, 64);
  __shared__ double sred[16];
  if ((t & 63) == 0) sred[t >> 6] = acc;
  __syncthreads();
  if (t == 0) {
    double tot = 0.0;
#pragma unroll
    for (int k = 0; k < 16; ++k) tot += sred[k];
    out[0] = (float)(tot * inv_total);
  }
}

extern "C" void kernel_launch(void* const* d_in, const int* in_sizes, int n_in,
                              void* d_out, int out_size, void* d_ws, size_t ws_size,
                              hipStream_t stream) {
  const float* kp = (const float*)d_in[0];
  const int* perm = (const int*)d_in[1];
  float* out = (float*)d_out;
  const int B = in_sizes[1];
  const double inv_total = 1.0 / ((double)B * (double)GEO_N * 3.0);

  const int NW = (B + 3) / 4;      // one wave per 4 batches
  float* partials = (float*)d_ws;  // NW floats
  const int grid = (NW + 3) / 4;   // 4 waves per 256-thread block
  geo_wave4<<<grid, 256, 0, stream>>>(kp, perm, partials, B, NW);
  geo_fin<<<1, 1024, 0, stream>>>(partials, out, NW, inv_total);
}

// Round 9
// 45.171 us; speedup vs baseline: 1.7576x; 1.1767x over previous
//
#include <hip/hip_runtime.h>
#include <math.h>

#define GEO_N 256

// Single-instruction HW approximations (~1 ulp) — error budget is huge
// (threshold 1.6e-2, measured absmax ~0 with exact ops).
__device__ __forceinline__ float frcp(float x) { return __builtin_amdgcn_rcpf(x); }
__device__ __forceinline__ float frsq(float x) { return __builtin_amdgcn_rsqf(x); }
__device__ __forceinline__ float fsqrtf_(float x) { return __builtin_amdgcn_sqrtf(x); }

__device__ __forceinline__ float wredf(float v) {
#pragma unroll
  for (int off = 32; off; off >>= 1) v += __shfl_xor(v, off, 64);
  return v;
}

// Halving butterfly: 16 per-lane values -> every lane holds ONE fully-reduced
// moment, index m(lane) = bitrev4(lane&15). Validated r6-r8.
__device__ __forceinline__ float hred16(const float r[16], int lane) {
  float v8[8], v4[4], v2[2], v1;
  const int b1 = lane & 1, b2 = (lane >> 1) & 1, b3 = (lane >> 2) & 1, b4 = (lane >> 3) & 1;
#pragma unroll
  for (int k = 0; k < 8; ++k) {
    float send = b1 ? r[k] : r[k + 8];
    float recv = __shfl_xor(send, 1, 64);
    v8[k] = (b1 ? r[k + 8] : r[k]) + recv;
  }
#pragma unroll
  for (int k = 0; k < 4; ++k) {
    float send = b2 ? v8[k] : v8[k + 4];
    float recv = __shfl_xor(send, 2, 64);
    v4[k] = (b2 ? v8[k + 4] : v8[k]) + recv;
  }
#pragma unroll
  for (int k = 0; k < 2; ++k) {
    float send = b3 ? v4[k] : v4[k + 2];
    float recv = __shfl_xor(send, 4, 64);
    v2[k] = (b3 ? v4[k + 2] : v4[k]) + recv;
  }
  {
    float send = b4 ? v2[0] : v2[1];
    float recv = __shfl_xor(send, 8, 64);
    v1 = (b4 ? v2[1] : v2[0]) + recv;
  }
  v1 += __shfl_xor(v1, 16, 64);
  v1 += __shfl_xor(v1, 32, 64);
  return v1;
}

// Branchless fast Jacobi rotation (both sides) + accumulate into V.
// t = sign(tau)/(|tau|+sqrt(1+tau^2)) via copysign; apq==0 & equal diag
// would give NaN -> cndmask skip-guard.
template <int P, int Q>
__device__ __forceinline__ void jrot(float G[3][3], float V[3][3]) {
  const float apq = G[P][Q];
  const float tau = (G[Q][Q] - G[P][P]) * 0.5f * frcp(apq);
  const float tt = fsqrtf_(1.0f + tau * tau);
  const float tr = frcp(tau + copysignf(tt, tau));
  const float cr = frsq(1.0f + tr * tr);
  const bool skip = fabsf(apq) < 1e-30f;
  const float c = skip ? 1.0f : cr;
  const float s = skip ? 0.0f : tr * cr;
#pragma unroll
  for (int k = 0; k < 3; ++k) {
    float gkp = G[k][P], gkq = G[k][Q];
    G[k][P] = c * gkp - s * gkq;
    G[k][Q] = s * gkp + c * gkq;
  }
#pragma unroll
  for (int k = 0; k < 3; ++k) {
    float gpk = G[P][k], gqk = G[Q][k];
    G[P][k] = c * gpk - s * gqk;
    G[Q][k] = s * gpk + c * gqk;
  }
#pragma unroll
  for (int k = 0; k < 3; ++k) {
    float vkp = V[k][P], vkq = V[k][Q];
    V[k][P] = c * vkp - s * vkq;
    V[k][Q] = s * vkp + c * vkq;
  }
}

// From 16 raw moment sums -> R(9), scale, T(3) packed into bc[0..12].
// Fast-math variant: fixed 4 sweeps (12 rotations), HW rcp/rsq/sqrt.
__device__ __forceinline__ void solve_rst(const float s0[16], float bc[13]) {
  const float invN = 1.0f / (float)GEO_N;
  const float smx = s0[0] * invN, smy = s0[1] * invN, smz = s0[2] * invN;
  const float dmx = s0[3] * invN, dmy = s0[4] * invN, dmz = s0[5] * invN;
  float A[3][3];
  A[0][0] = s0[6] * invN - dmx * smx;  A[0][1] = s0[7] * invN - dmx * smy;  A[0][2] = s0[8] * invN - dmx * smz;
  A[1][0] = s0[9] * invN - dmy * smx;  A[1][1] = s0[10] * invN - dmy * smy; A[1][2] = s0[11] * invN - dmy * smz;
  A[2][0] = s0[12] * invN - dmz * smx; A[2][1] = s0[13] * invN - dmz * smy; A[2][2] = s0[14] * invN - dmz * smz;
  const float var_sum = s0[15] * invN - (smx * smx + smy * smy + smz * smz);

  float G[3][3];
#pragma unroll
  for (int i = 0; i < 3; ++i)
#pragma unroll
    for (int j = 0; j < 3; ++j)
      G[i][j] = A[0][i] * A[0][j] + A[1][i] * A[1][j] + A[2][i] * A[2][j];
  float V[3][3] = {{1, 0, 0}, {0, 1, 0}, {0, 0, 1}};
#pragma unroll
  for (int sweep = 0; sweep < 4; ++sweep) {
    jrot<0, 1>(G, V);
    jrot<0, 2>(G, V);
    jrot<1, 2>(G, V);
  }
  float l0 = G[0][0], l1 = G[1][1], l2 = G[2][2];
  if (l0 < l1) { float tl = l0; l0 = l1; l1 = tl;
#pragma unroll
    for (int k = 0; k < 3; ++k) { float tv = V[k][0]; V[k][0] = V[k][1]; V[k][1] = tv; } }
  if (l0 < l2) { float tl = l0; l0 = l2; l2 = tl;
#pragma unroll
    for (int k = 0; k < 3; ++k) { float tv = V[k][0]; V[k][0] = V[k][2]; V[k][2] = tv; } }
  if (l1 < l2) { float tl = l1; l1 = l2; l2 = tl;
#pragma unroll
    for (int k = 0; k < 3; ++k) { float tv = V[k][1]; V[k][1] = V[k][2]; V[k][2] = tv; } }
  const float sig0 = fsqrtf_(fmaxf(l0, 0.0f));
  const float sig1 = fsqrtf_(fmaxf(l1, 0.0f));
  const float sig2 = fsqrtf_(fmaxf(l2, 0.0f));

  float v0[3] = {V[0][0], V[1][0], V[2][0]};
  float v1[3] = {V[0][1], V[1][1], V[2][1]};
  float v2[3] = {V[0][2], V[1][2], V[2][2]};
  float u0[3], u1[3], u2r[3];
#pragma unroll
  for (int i = 0; i < 3; ++i) {
    u0[i]  = A[i][0] * v0[0] + A[i][1] * v0[1] + A[i][2] * v0[2];
    u1[i]  = A[i][0] * v1[0] + A[i][1] * v1[1] + A[i][2] * v1[2];
    u2r[i] = A[i][0] * v2[0] + A[i][1] * v2[1] + A[i][2] * v2[2];
  }
  float n0 = u0[0] * u0[0] + u0[1] * u0[1] + u0[2] * u0[2];
  if (n0 > 1e-28f) { float inv = frsq(n0); u0[0] *= inv; u0[1] *= inv; u0[2] *= inv; }
  else { u0[0] = 1.0f; u0[1] = 0.0f; u0[2] = 0.0f; }
  float d01 = u1[0] * u0[0] + u1[1] * u0[1] + u1[2] * u0[2];
  u1[0] -= d01 * u0[0]; u1[1] -= d01 * u0[1]; u1[2] -= d01 * u0[2];
  float n1 = u1[0] * u1[0] + u1[1] * u1[1] + u1[2] * u1[2];
  if (n1 > 1e-28f) { float inv = frsq(n1); u1[0] *= inv; u1[1] *= inv; u1[2] *= inv; }
  else {
    float ex[3] = {1, 0, 0}, ey[3] = {0, 1, 0};
    const float* e = (fabsf(u0[0]) < 0.9f) ? ex : ey;
    u1[0] = u0[1] * e[2] - u0[2] * e[1];
    u1[1] = u0[2] * e[0] - u0[0] * e[2];
    u1[2] = u0[0] * e[1] - u0[1] * e[0];
    float nn = u1[0] * u1[0] + u1[1] * u1[1] + u1[2] * u1[2];
    float inv = frsq(nn);
    u1[0] *= inv; u1[1] *= inv; u1[2] *= inv;
  }
  float u2[3] = {u0[1] * u1[2] - u0[2] * u1[1],
                 u0[2] * u1[0] - u0[0] * u1[2],
                 u0[0] * u1[1] - u0[1] * u1[0]};
  float d2 = u2[0] * u2r[0] + u2[1] * u2r[1] + u2[2] * u2r[2];
  if (d2 < 0.0f) { u2[0] = -u2[0]; u2[1] = -u2[1]; u2[2] = -u2[2]; }

  const float scale = (sig0 + sig1 + sig2) * frcp(fmaxf(var_sum, 1e-30f));
  float R[3][3];
#pragma unroll
  for (int i = 0; i < 3; ++i)
#pragma unroll
    for (int j = 0; j < 3; ++j)
      R[i][j] = u0[i] * v0[j] + u1[i] * v1[j] + u2[i] * v2[j];
  const float Tx = dmx - scale * (R[0][0] * smx + R[0][1] * smy + R[0][2] * smz);
  const float Ty = dmy - scale * (R[1][0] * smx + R[1][1] * smy + R[1][2] * smz);
  const float Tz = dmz - scale * (R[2][0] * smx + R[2][1] * smy + R[2][2] * smz);
#pragma unroll
  for (int i = 0; i < 3; ++i)
#pragma unroll
    for (int j = 0; j < 3; ++j) bc[3 * i + j] = R[i][j];
  bc[9] = scale; bc[10] = Tx; bc[11] = Ty; bc[12] = Tz;
}

// ---------- Single-pass, barrier-free: one WAVE = 4 batches, all in VGPRs.
// Structure validated r8 (absmax 0). This round: fast-math solve.
__global__ __launch_bounds__(256) void geo_wave4(const float* __restrict__ kp,
                                                 const int* __restrict__ perm,
                                                 float* __restrict__ partials,
                                                 int B, int NW) {
  const int wid = (blockIdx.x << 2) | (threadIdx.x >> 6);
  if (wid >= NW) return;  // no barriers in this kernel -> early return safe
  const int lane = threadIdx.x & 63;
  const int b0 = wid * 4;
  const float4* base = (const float4*)kp;

  int pm[4];
#pragma unroll
  for (int i = 0; i < 4; ++i) pm[i] = perm[min(b0 + i, B - 1)];

  // ---- Load all 4 batches (src + permuted dst): 24 loads in flight ----
  float4 S[4][3], D[4][3];
#pragma unroll
  for (int i = 0; i < 4; ++i) {
    const int bb = min(b0 + i, B - 1);
    const float4* s4 = base + (size_t)bb * 192 + lane * 3;
    const float4* d4 = base + (size_t)pm[i] * 192 + lane * 3;
    S[i][0] = s4[0]; S[i][1] = s4[1]; S[i][2] = s4[2];
    D[i][0] = d4[0]; D[i][1] = d4[1]; D[i][2] = d4[2];
  }

  // ---- Moments per batch; park batch i's reduced moments in lane-group i ----
  float parked = 0.0f;
#pragma unroll
  for (int i = 0; i < 4; ++i) {
    const float s[12] = {S[i][0].x, S[i][0].y, S[i][0].z, S[i][0].w,
                         S[i][1].x, S[i][1].y, S[i][1].z, S[i][1].w,
                         S[i][2].x, S[i][2].y, S[i][2].z, S[i][2].w};
    const float d[12] = {D[i][0].x, D[i][0].y, D[i][0].z, D[i][0].w,
                         D[i][1].x, D[i][1].y, D[i][1].z, D[i][1].w,
                         D[i][2].x, D[i][2].y, D[i][2].z, D[i][2].w};
    float r[16];
#pragma unroll
    for (int k = 0; k < 16; ++k) r[k] = 0.0f;
#pragma unroll
    for (int p = 0; p < 4; ++p) {
      const float sx = s[3 * p + 0], sy = s[3 * p + 1], sz = s[3 * p + 2];
      const float dx = d[3 * p + 0], dy = d[3 * p + 1], dz = d[3 * p + 2];
      r[0] += sx; r[1] += sy; r[2] += sz;
      r[3] += dx; r[4] += dy; r[5] += dz;
      r[6] += dx * sx; r[7] += dx * sy; r[8] += dx * sz;
      r[9] += dy * sx; r[10] += dy * sy; r[11] += dy * sz;
      r[12] += dz * sx; r[13] += dz * sy; r[14] += dz * sz;
      r[15] += sx * sx + sy * sy + sz * sz;
    }
    const float v = hred16(r, lane);  // lane j: moment bitrev4(j&15), all j
    if ((lane >> 4) == i) parked = v;
  }

  // ---- shfl-transpose: lane t gathers batch (t&3)'s 16 moments in order ----
  constexpr int br[16] = {0, 8, 4, 12, 2, 10, 6, 14, 1, 9, 5, 13, 3, 11, 7, 15};
  float s0[16];
#pragma unroll
  for (int k = 0; k < 16; ++k)
    s0[k] = __shfl(parked, ((lane & 3) << 4) | br[k], 64);

  // ---- One solve per wave (lane t solves batch b0 + (t&3)) ----
  float bc[13];
  solve_rst(s0, bc);

  // ---- Errors from live registers; params broadcast from lane i ----
  float acc = 0.0f;
#pragma unroll
  for (int i = 0; i < 4; ++i) {
    const float R00 = __shfl(bc[0], i, 64), R01 = __shfl(bc[1], i, 64), R02 = __shfl(bc[2], i, 64);
    const float R10 = __shfl(bc[3], i, 64), R11 = __shfl(bc[4], i, 64), R12 = __shfl(bc[5], i, 64);
    const float R20 = __shfl(bc[6], i, 64), R21 = __shfl(bc[7], i, 64), R22 = __shfl(bc[8], i, 64);
    const float sc  = __shfl(bc[9], i, 64);
    const float Tx  = __shfl(bc[10], i, 64), Ty = __shfl(bc[11], i, 64), Tz = __shfl(bc[12], i, 64);
    const float s[12] = {S[i][0].x, S[i][0].y, S[i][0].z, S[i][0].w,
                         S[i][1].x, S[i][1].y, S[i][1].z, S[i][1].w,
                         S[i][2].x, S[i][2].y, S[i][2].z, S[i][2].w};
    const float d[12] = {D[i][0].x, D[i][0].y, D[i][0].z, D[i][0].w,
                         D[i][1].x, D[i][1].y, D[i][1].z, D[i][1].w,
                         D[i][2].x, D[i][2].y, D[i][2].z, D[i][2].w};
    float a = 0.0f;
#pragma unroll
    for (int q = 0; q < 4; ++q) {
      const float sx = s[3 * q + 0], sy = s[3 * q + 1], sz = s[3 * q + 2];
      const float dx = d[3 * q + 0], dy = d[3 * q + 1], dz = d[3 * q + 2];
      const float e0 = sc * (R00 * sx + R01 * sy + R02 * sz) + Tx - dx;
      const float e1 = sc * (R10 * sx + R11 * sy + R12 * sz) + Ty - dy;
      const float e2 = sc * (R20 * sx + R21 * sy + R22 * sz) + Tz - dz;
      a += fabsf(e0) + fabsf(e1) + fabsf(e2);
    }
    if (b0 + i < B) acc += a;  // mask clamped tail batches
  }
  acc = wredf(acc);
  if (lane == 0) partials[wid] = acc;
}

// ---------- Final reduce ----------
__global__ __launch_bounds__(1024) void geo_fin(const float* __restrict__ partials,
                                                float* __restrict__ out, int n,
                                                double inv_total) {
  const int t = threadIdx.x;
  double acc = 0.0;
  for (int i = t; i < n; i += 1024) acc += (double)partials[i];
#pragma unroll
  for (int off = 32; off; off >>= 1) acc += __shfl_xor(acc, off, 64);
  __shared__ double sred[16];
  if ((t & 63) == 0) sred[t >> 6] = acc;
  __syncthreads();
  if (t == 0) {
    double tot = 0.0;
#pragma unroll
    for (int k = 0; k < 16; ++k) tot += sred[k];
    out[0] = (float)(tot * inv_total);
  }
}

extern "C" void kernel_launch(void* const* d_in, const int* in_sizes, int n_in,
                              void* d_out, int out_size, void* d_ws, size_t ws_size,
                              hipStream_t stream) {
  const float* kp = (const float*)d_in[0];
  const int* perm = (const int*)d_in[1];
  float* out = (float*)d_out;
  const int B = in_sizes[1];
  const double inv_total = 1.0 / ((double)B * (double)GEO_N * 3.0);

  const int NW = (B + 3) / 4;      // one wave per 4 batches
  float* partials = (float*)d_ws;  // NW floats
  const int grid = (NW + 3) / 4;   // 4 waves per 256-thread block
  geo_wave4<<<grid, 256, 0, stream>>>(kp, perm, partials, B, NW);
  geo_fin<<<1, 1024, 0, stream>>>(partials, out, NW, inv_total);
}